// Round 8
// baseline (166.377 us; speedup 1.0000x reference)
//
#include <hip/hip_runtime.h>

#define HW 1024
#define CC 256
#define NB 32
constexpr float INV_T = 1.0f / 0.07f;

typedef __attribute__((ext_vector_type(8))) short short8;
typedef __attribute__((ext_vector_type(4))) float f32x4;

__device__ __forceinline__ ushort f2bf(float x) {
    uint32_t u = __float_as_uint(x);
    uint32_t r = (u + 0x7fffu + ((u >> 16) & 1u)) >> 16;
    return (ushort)r;
}
__device__ __forceinline__ float bf2f(ushort h) {
    return __uint_as_float(((uint32_t)h) << 16);
}

__device__ __forceinline__ void gload16(const void* g, void* l) {
    __builtin_amdgcn_global_load_lds(
        (const __attribute__((address_space(1))) uint32_t*)g,
        (__attribute__((address_space(3))) uint32_t*)l, 16, 0, 0);
}

// ---------------- Convert + transpose: X[b][c][hw] f32 -> hi/lo[b][hw][c] bf16 ----------------
__global__ __launch_bounds__(256) void convert_kernel(const float* __restrict__ A,
                                                      const float* __restrict__ Bm,
                                                      ushort* __restrict__ Qhi,
                                                      ushort* __restrict__ Qlo,
                                                      ushort* __restrict__ Phi,
                                                      ushort* __restrict__ Plo) {
    int blk = blockIdx.x;
    int which = blk >= NB * 64;
    if (which) blk -= NB * 64;
    const float* X = which ? Bm : A;
    ushort* hi = which ? Phi : Qhi;
    ushort* lo = which ? Plo : Qlo;

    int b = blk >> 6;
    int tile = blk & 63;
    int c0 = (tile >> 4) * 64;
    int h0 = (tile & 15) * 64;

    __shared__ ushort Th[64][76];
    __shared__ ushort Tl[64][76];

    int tid = threadIdx.x;
    const float* Xb = X + ((size_t)b * CC + c0) * HW + h0;

#pragma unroll
    for (int p = 0; p < 4; ++p) {
        int cr = p * 16 + (tid >> 4);
        int hcol = (tid & 15) * 4;
        float4 v = *reinterpret_cast<const float4*>(&Xb[(size_t)cr * HW + hcol]);
        float xs[4] = {v.x, v.y, v.z, v.w};
#pragma unroll
        for (int j = 0; j < 4; ++j) {
            float x = xs[j];
            ushort h_ = f2bf(x);
            float hf = bf2f(h_);
            ushort l_ = f2bf(x - hf);
            Th[hcol + j][cr] = h_;
            Tl[hcol + j][cr] = l_;
        }
    }
    __syncthreads();
    size_t obase = ((size_t)b * HW + h0) * CC + c0;
#pragma unroll
    for (int q = 0; q < 4; ++q) {
        int hr = q * 16 + (tid >> 4);
        int cc = (tid & 15) * 4;
        ushort4 vh = *reinterpret_cast<const ushort4*>(&Th[hr][cc]);
        ushort4 vl = *reinterpret_cast<const ushort4*>(&Tl[hr][cc]);
        *reinterpret_cast<ushort4*>(&hi[obase + (size_t)hr * CC + cc]) = vh;
        *reinterpret_cast<ushort4*>(&lo[obase + (size_t)hr * CC + cc]) = vl;
    }
}

// ---------------- Kernel 1: split-bf16 MFMA GEMM, 256x256 tile, 8-wave, 4-phase/K-tile -------
// N[b,i,k] = (1/T) * sum_c P[b,i,c] * Q[b,k,c]; passes hi*hi + hi*lo + lo*hi share staging.
// LDS: 2 dbuf x 4 panels x 16KB (panel = 256 rows x 32 k, rows packed 2/128B-row, XOR-swizzled)
__global__ __launch_bounds__(512, 2) void gemm_mfma(const ushort* __restrict__ Phi,
                                                    const ushort* __restrict__ Plo,
                                                    const ushort* __restrict__ Qhi,
                                                    const ushort* __restrict__ Qlo,
                                                    float* __restrict__ Nout,
                                                    float* __restrict__ rpm,
                                                    float* __restrict__ rps,
                                                    float* __restrict__ cpm,
                                                    float* __restrict__ cps) {
    int bid = blockIdx.x;
    int swz = (bid & 7) * 64 + (bid >> 3);    // 512 blocks, %8==0 -> bijective XCD swizzle
    int b = swz >> 4;
    int tile = swz & 15;
    int i0 = (tile >> 2) * 256;
    int k0 = (tile & 3) * 256;

    __shared__ char S[2][4][16384];           // [buf][panel 0=Phi 1=Plo 2=Qhi 3=Qlo]

    int tid = threadIdx.x;
    int lane = tid & 63;
    int w = tid >> 6;                         // 0..7
    int wr = w >> 2, wc = w & 3;              // 2M x 4N wave grid; wave owns 128x64
    int l15 = lane & 15, lg = lane >> 4;

    f32x4 acc[8][4];
#pragma unroll
    for (int f = 0; f < 8; ++f)
#pragma unroll
        for (int g = 0; g < 4; ++g)
#pragma unroll
            for (int r = 0; r < 4; ++r) acc[f][g][r] = 0.0f;

    size_t bbase = (size_t)b * HW * CC;
    const char* gp0 = (const char*)(Phi + bbase + (size_t)i0 * CC);
    const char* gp1 = (const char*)(Plo + bbase + (size_t)i0 * CC);
    const char* gp2 = (const char*)(Qhi + bbase + (size_t)k0 * CC);
    const char* gp3 = (const char*)(Qlo + bbase + (size_t)k0 * CC);

    // stage one 16KB panel (256 rows x 64B) for K-tile at byte offset `co`;
    // LDS dest linear (wave-uniform base), global source inverse-swizzled.
    auto stage = [&](const char* g, char* pbase) {
#pragma unroll
        for (int it = 0; it < 2; ++it) {
            int o = it * 8192 + tid * 16;
            int ldsrow = o >> 7;                       // 0..127
            int ub = (o & 127) ^ ((ldsrow & 7) << 4);  // unswizzled byte-in-row
            int grow = ldsrow + ((ub >> 6) << 7);      // global row 0..255
            int gcol = ub & 63;
            gload16(g + grow * 512 + gcol, pbase + it * 8192 + w * 1024);
        }
    };

    // prologue: stage K-tile 0 into buf 0
    stage(gp0, &S[0][0][0]);
    stage(gp1, &S[0][1][0]);
    stage(gp2, &S[0][2][0]);
    stage(gp3, &S[0][3][0]);
    asm volatile("s_waitcnt vmcnt(0)" ::: "memory");
    __builtin_amdgcn_s_barrier();
    __builtin_amdgcn_sched_barrier(0);

    int aoff = ((wr << 6) + (lg << 4)) ^ ((l15 & 7) << 4);   // A byte-in-row (hi-half = wr)

    for (int t = 0; t < 8; ++t) {
        char* Scur = &S[t & 1][0][0];
        char* Snxt = &S[(t + 1) & 1][0][0];
        int co = (t + 1) * 64;                // next K-tile byte offset (32 elems * 2B)
        short8 qh[4], ql[4];

#pragma unroll
        for (int q = 0; q < 4; ++q) {
            // ---- ds-reads for this phase ----
            if (q == 0) {
#pragma unroll
                for (int g = 0; g < 4; ++g) {
                    int rb = wc * 64 + g * 16 + l15;          // Q row (= output col) 0..255
                    int lr = rb & 127;
                    int ob = lr * 128 + ((((rb >> 7) << 6) + (lg << 4)) ^ ((lr & 7) << 4));
                    qh[g] = *(const short8*)(Scur + 2 * 16384 + ob);
                    ql[g] = *(const short8*)(Scur + 3 * 16384 + ob);
                }
            }
            short8 ah[2], al[2];
#pragma unroll
            for (int u = 0; u < 2; ++u) {
                int oa = ((2 * q + u) * 16 + l15) * 128 + aoff;
                ah[u] = *(const short8*)(Scur + oa);
                al[u] = *(const short8*)(Scur + 16384 + oa);
            }
            // ---- stage one panel of next K-tile ----
            if (t < 7) {
                const char* gq = (q == 0 ? gp0 : q == 1 ? gp1 : q == 2 ? gp2 : gp3) + co;
                stage(gq, Snxt + q * 16384);
            }
            __builtin_amdgcn_s_barrier();
            asm volatile("s_waitcnt lgkmcnt(0)" ::: "memory");
            __builtin_amdgcn_sched_barrier(0);
            __builtin_amdgcn_s_setprio(1);
#pragma unroll
            for (int u = 0; u < 2; ++u)
#pragma unroll
                for (int g = 0; g < 4; ++g)
                    acc[2 * q + u][g] = __builtin_amdgcn_mfma_f32_16x16x32_bf16(ah[u], qh[g], acc[2 * q + u][g], 0, 0, 0);
#pragma unroll
            for (int u = 0; u < 2; ++u)
#pragma unroll
                for (int g = 0; g < 4; ++g)
                    acc[2 * q + u][g] = __builtin_amdgcn_mfma_f32_16x16x32_bf16(ah[u], ql[g], acc[2 * q + u][g], 0, 0, 0);
#pragma unroll
            for (int u = 0; u < 2; ++u)
#pragma unroll
                for (int g = 0; g < 4; ++g)
                    acc[2 * q + u][g] = __builtin_amdgcn_mfma_f32_16x16x32_bf16(al[u], qh[g], acc[2 * q + u][g], 0, 0, 0);
            __builtin_amdgcn_s_setprio(0);
            if (q < 3) {
                __builtin_amdgcn_s_barrier();
            } else {
                asm volatile("s_waitcnt vmcnt(0)" ::: "memory");   // stage(t+1) landed (issued ~96 MFMA ago)
                __builtin_amdgcn_s_barrier();
                __builtin_amdgcn_sched_barrier(0);
            }
        }
    }

    // ---- write N tile ----
    float* Nb = Nout + (size_t)b * HW * HW;
#pragma unroll
    for (int f = 0; f < 8; ++f) {
        int i = i0 + wr * 128 + f * 16 + lg * 4;
#pragma unroll
        for (int g = 0; g < 4; ++g) {
            int k = k0 + wc * 64 + g * 16 + l15;
#pragma unroll
            for (int r = 0; r < 4; ++r)
                Nb[(size_t)(i + r) * HW + k] = acc[f][g][r] * INV_T;
        }
    }

    // ---- fused row partial stats (wave's 128 rows x 64 cols) ----
    int kt = (tile & 3) * 4 + wc;             // 0..15 col-block-of-64
    int it = (tile >> 2) * 2 + wr;            // 0..7  row-block-of-128
    size_t rbase = ((size_t)b * 16 + kt) * HW;
    size_t cbase = ((size_t)b * 8 + it) * HW;

#pragma unroll
    for (int f = 0; f < 8; ++f) {
#pragma unroll
        for (int r = 0; r < 4; ++r) {
            float x0 = acc[f][0][r] * INV_T;
            float x1 = acc[f][1][r] * INV_T;
            float x2 = acc[f][2][r] * INV_T;
            float x3 = acc[f][3][r] * INV_T;
            float m = fmaxf(fmaxf(x0, x1), fmaxf(x2, x3));
#pragma unroll
            for (int off = 1; off < 16; off <<= 1) m = fmaxf(m, __shfl_xor(m, off));
            float s = __expf(x0 - m) + __expf(x1 - m) + __expf(x2 - m) + __expf(x3 - m);
#pragma unroll
            for (int off = 1; off < 16; off <<= 1) s += __shfl_xor(s, off);
            if (l15 == 0) {
                int i = i0 + wr * 128 + f * 16 + lg * 4 + r;
                rpm[rbase + i] = m;
                rps[rbase + i] = s;
            }
        }
    }

    // ---- fused col partial stats (wave's 128 rows per col) ----
#pragma unroll
    for (int g = 0; g < 4; ++g) {
        float m = -INFINITY;
#pragma unroll
        for (int f = 0; f < 8; ++f)
#pragma unroll
            for (int r = 0; r < 4; ++r) m = fmaxf(m, acc[f][g][r] * INV_T);
        m = fmaxf(m, __shfl_xor(m, 16));
        m = fmaxf(m, __shfl_xor(m, 32));
        float s = 0.f;
#pragma unroll
        for (int f = 0; f < 8; ++f)
#pragma unroll
            for (int r = 0; r < 4; ++r) s += __expf(acc[f][g][r] * INV_T - m);
        s += __shfl_xor(s, 16);
        s += __shfl_xor(s, 32);
        if (lane < 16) {
            int k = k0 + wc * 64 + g * 16 + lane;
            cpm[cbase + k] = m;
            cps[cbase + k] = s;
        }
    }
}

// ---------------- Kernel 2: combine partials ----------------
// blocks [0,128): rows (16 partials); [128,256): cols (8 partials)
__global__ __launch_bounds__(256) void combine_kernel(const float* __restrict__ rpm,
                                                      const float* __restrict__ rps,
                                                      const float* __restrict__ cpm,
                                                      const float* __restrict__ cps,
                                                      float* __restrict__ rmax,
                                                      float* __restrict__ rsuminv,
                                                      float* __restrict__ cmax,
                                                      float* __restrict__ csuminv) {
    int blk = blockIdx.x;
    int iscol = blk >= 128;
    if (iscol) blk -= 128;
    int idx = blk * 256 + threadIdx.x;
    int b = idx >> 10;
    int e = idx & 1023;
    const float* pm = iscol ? cpm : rpm;
    const float* ps = iscol ? cps : rps;
    int nt = iscol ? 8 : 16;
    size_t base = (size_t)b * nt * HW + e;
    float m = -INFINITY;
    for (int t = 0; t < 16; ++t) {
        if (t >= nt) break;
        m = fmaxf(m, pm[base + (size_t)t * HW]);
    }
    float s = 0.f;
    for (int t = 0; t < 16; ++t) {
        if (t >= nt) break;
        s += ps[base + (size_t)t * HW] * __expf(pm[base + (size_t)t * HW] - m);
    }
    if (iscol) {
        cmax[idx] = m;
        csuminv[idx] = 1.0f / s;
    } else {
        rmax[idx] = m;
        rsuminv[idx] = 1.0f / s;
    }
}

// ---------------- Kernel 3: P = exp(2x-rm-cm)*rsinv*csinv, transposed write ----------------
__global__ __launch_bounds__(256) void final_kernel(const float* __restrict__ N,
                                                    const float* __restrict__ rm,
                                                    const float* __restrict__ rsi,
                                                    const float* __restrict__ cm,
                                                    const float* __restrict__ csi,
                                                    float* __restrict__ out) {
    int blk = blockIdx.x;
    int b = blk >> 8;
    int tile = blk & 255;
    int i0 = (tile >> 4) * 64;
    int k0 = (tile & 15) * 64;
    const float* Nb = N + (size_t)b * HW * HW;
    float* outb = out + (size_t)b * HW * HW;
    const float* rmb = rm + b * HW;
    const float* rsib = rsi + b * HW;
    const float* cmb = cm + b * HW;
    const float* csib = csi + b * HW;

    __shared__ float tileP[64][65];

    int t = threadIdx.x;
    int tr = t >> 4;
    int tc4 = (t & 15) * 4;

    float4 cm4 = *reinterpret_cast<const float4*>(&cmb[k0 + tc4]);
    float4 cs4 = *reinterpret_cast<const float4*>(&csib[k0 + tc4]);
    float cmv[4] = {cm4.x, cm4.y, cm4.z, cm4.w};
    float csv[4] = {cs4.x, cs4.y, cs4.z, cs4.w};

#pragma unroll
    for (int rr = 0; rr < 4; ++rr) {
        int il = tr + rr * 16;
        int i = i0 + il;
        float rmax = rmb[i];
        float rsinv = rsib[i];
        float4 v = *reinterpret_cast<const float4*>(&Nb[(size_t)i * HW + k0 + tc4]);
        float x[4] = {v.x, v.y, v.z, v.w};
#pragma unroll
        for (int j = 0; j < 4; ++j) {
            tileP[il][tc4 + j] = __expf(x[j] + x[j] - rmax - cmv[j]) * rsinv * csv[j];
        }
    }
    __syncthreads();
#pragma unroll
    for (int rr = 0; rr < 4; ++rr) {
        int kl = tr + rr * 16;
        int k = k0 + kl;
        int tk = ((k & 31) << 5) | (k >> 5);
        float4 v;
        v.x = tileP[tc4 + 0][kl];
        v.y = tileP[tc4 + 1][kl];
        v.z = tileP[tc4 + 2][kl];
        v.w = tileP[tc4 + 3][kl];
        *reinterpret_cast<float4*>(&outb[(size_t)tk * HW + i0 + tc4]) = v;
    }
}

extern "C" void kernel_launch(void* const* d_in, const int* in_sizes, int n_in,
                              void* d_out, int out_size, void* d_ws, size_t ws_size,
                              hipStream_t stream) {
    const float* A = (const float*)d_in[0];   // feature_A [32,256,32,32]
    const float* Bm = (const float*)d_in[1];  // feature_B [32,256,32,32]
    float* out = (float*)d_out;

    float* ws = (float*)d_ws;
    const size_t n_elems = (size_t)NB * HW * HW;       // 33.5M
    const size_t stat_n = (size_t)NB * HW;             // 32768
    const size_t rpart_n = (size_t)NB * 16 * HW;       // 524288
    const size_t cpart_n = (size_t)NB * 8 * HW;        // 262144
    float* N = ws;
    float* rmax = N + n_elems;
    float* rsuminv = rmax + stat_n;
    float* cmax = rsuminv + stat_n;
    float* csuminv = cmax + stat_n;
    float* rpm = csuminv + stat_n;
    float* rps = rpm + rpart_n;
    float* cpm = rps + rpart_n;
    float* cps = cpm + cpart_n;
    ushort* Qhi = (ushort*)(cps + cpart_n);
    ushort* Qlo = Qhi + (size_t)NB * HW * CC;
    ushort* Phi = Qlo + (size_t)NB * HW * CC;
    ushort* Plo = Phi + (size_t)NB * HW * CC;

    hipLaunchKernelGGL(convert_kernel, dim3(2 * NB * 64), dim3(256), 0, stream,
                       A, Bm, Qhi, Qlo, Phi, Plo);
    hipLaunchKernelGGL(gemm_mfma, dim3(512), dim3(512), 0, stream,
                       Phi, Plo, Qhi, Qlo, N, rpm, rps, cpm, cps);
    hipLaunchKernelGGL(combine_kernel, dim3(256), dim3(256), 0, stream,
                       rpm, rps, cpm, cps, rmax, rsuminv, cmax, csuminv);
    hipLaunchKernelGGL(final_kernel, dim3(NB * 256), dim3(256), 0, stream,
                       N, rmax, rsuminv, cmax, csuminv, out);
}